// Round 1
// baseline (251.824 us; speedup 1.0000x reference)
//
#include <hip/hip_runtime.h>
#include <hip/hip_bf16.h>

// TokenEmbedding segment-sum, MI355X.
// out[b,t,:] = sum over w with tok[b,w]==t of seq[b,w,:]
// tok is sorted per batch -> each token's wordpieces are a contiguous run.
// One block per (b,t): binary-search run bounds (block-uniform -> scalar
// loads, index row is 16KB and L1/L2 resident), then gather-sum the run
// with float4 loads. Each input row read once, each output row written once.
// Empty runs write zeros (d_out is poisoned, no separate memset needed).

#define B_DIM 8
#define L_DIM 4096
#define H_DIM 1024

__global__ __launch_bounds__(256) void token_seg_sum_kernel(
    const float* __restrict__ seq,   // [B, L, H] fp32
    const int* __restrict__ tok,     // [B, L] int32, sorted per batch
    float* __restrict__ out)         // [B, L, H] fp32
{
    const int bt = blockIdx.x;           // 0 .. B*L-1
    const int b  = bt >> 12;             // / 4096
    const int t  = bt & (L_DIM - 1);     // % 4096

    const int* __restrict__ idx = tok + (size_t)b * L_DIM;

    // lower_bound(t)
    int lo = 0, hi = L_DIM;
    while (lo < hi) {
        int mid = (lo + hi) >> 1;
        if (idx[mid] < t) lo = mid + 1; else hi = mid;
    }
    const int start = lo;
    // upper_bound(t)
    hi = L_DIM;
    while (lo < hi) {
        int mid = (lo + hi) >> 1;
        if (idx[mid] <= t) lo = mid + 1; else hi = mid;
    }
    const int end = lo;

    const int tid = threadIdx.x;                 // 0..255, each owns a float4
    const float4* __restrict__ base =
        (const float4*)(seq + (size_t)b * L_DIM * H_DIM);

    float4 acc = make_float4(0.f, 0.f, 0.f, 0.f);
    for (int w = start; w < end; ++w) {
        float4 v = base[(size_t)w * (H_DIM / 4) + tid];
        acc.x += v.x; acc.y += v.y; acc.z += v.z; acc.w += v.w;
    }

    ((float4*)out)[(size_t)bt * (H_DIM / 4) + tid] = acc;
}

extern "C" void kernel_launch(void* const* d_in, const int* in_sizes, int n_in,
                              void* d_out, int out_size, void* d_ws, size_t ws_size,
                              hipStream_t stream) {
    const float* seq = (const float*)d_in[0];
    const int*   tok = (const int*)d_in[1];
    float*       out = (float*)d_out;

    dim3 grid(B_DIM * L_DIM);   // 32768 blocks, one per (b, t)
    dim3 block(256);            // 256 lanes x float4 = one 4KB H row
    token_seg_sum_kernel<<<grid, block, 0, stream>>>(seq, tok, out);
}

// Round 2
// 232.710 us; speedup vs baseline: 1.0821x; 1.0821x over previous
//
#include <hip/hip_runtime.h>
#include <hip/hip_bf16.h>

// TokenEmbedding segment-sum, MI355X. Two-phase gather:
//  Phase 1: build lower-bound table start[b][t] (t in 0..L) via boundary
//           scatter (tok is sorted per batch) -> kills the per-block binary
//           search that made round-1 latency-bound (24 dependent loads).
//  Phase 2: one block per (b,t); 2 broadcast loads give [start, end), then
//           float4 gather-sum of the run and one coalesced row store.
// Each input row read once, each output row written once. Empty runs write
// zeros (handles poisoned d_out without a memset pass).

#define B_DIM 8
#define L_DIM 4096
#define H_DIM 1024
#define LP1   (L_DIM + 1)

__global__ __launch_bounds__(256) void build_starts_kernel(
    const int* __restrict__ tok,   // [B, L] sorted per batch
    int* __restrict__ start)       // [B, L+1]
{
    const int gid = blockIdx.x * 256 + threadIdx.x;   // 0 .. B*L-1
    const int b = gid >> 12;
    const int w = gid & (L_DIM - 1);

    const int* __restrict__ row = tok + (size_t)b * L_DIM;
    const int cur  = row[w];
    const int prev = (w > 0) ? row[w - 1] : -1;

    int* __restrict__ srow = start + (size_t)b * LP1;
    for (int t = prev + 1; t <= cur; ++t) srow[t] = w;
    if (w == L_DIM - 1) {
        for (int t = cur + 1; t <= L_DIM; ++t) srow[t] = L_DIM;
    }
}

__global__ __launch_bounds__(256) void token_seg_sum_kernel(
    const float* __restrict__ seq,   // [B, L, H] fp32
    const int* __restrict__ start,   // [B, L+1]
    float* __restrict__ out)         // [B, L, H] fp32
{
    const int bt = blockIdx.x;           // 0 .. B*L-1
    const int b  = bt >> 12;
    const int t  = bt & (L_DIM - 1);

    const int* __restrict__ srow = start + (size_t)b * LP1;
    const int s = srow[t];
    const int e = srow[t + 1];

    const int tid = threadIdx.x;                 // each lane owns one float4
    const float4* __restrict__ base =
        (const float4*)(seq + (size_t)b * L_DIM * H_DIM);

    float4 acc = make_float4(0.f, 0.f, 0.f, 0.f);
    for (int w = s; w < e; ++w) {
        float4 v = base[(size_t)w * (H_DIM / 4) + tid];
        acc.x += v.x; acc.y += v.y; acc.z += v.z; acc.w += v.w;
    }

    ((float4*)out)[(size_t)bt * (H_DIM / 4) + tid] = acc;
}

extern "C" void kernel_launch(void* const* d_in, const int* in_sizes, int n_in,
                              void* d_out, int out_size, void* d_ws, size_t ws_size,
                              hipStream_t stream) {
    const float* seq = (const float*)d_in[0];
    const int*   tok = (const int*)d_in[1];
    float*       out = (float*)d_out;
    int*         start = (int*)d_ws;            // B*(L+1) ints = 131 KB

    build_starts_kernel<<<dim3(B_DIM * L_DIM / 256), dim3(256), 0, stream>>>(tok, start);
    token_seg_sum_kernel<<<dim3(B_DIM * L_DIM), dim3(256), 0, stream>>>(seq, start, out);
}